// Round 17
// baseline (84.767 us; speedup 1.0000x reference)
//
#include <hip/hip_runtime.h>

typedef __bf16 bf16;
typedef __bf16 bf16x8 __attribute__((ext_vector_type(8)));
typedef __bf16 bf16x4 __attribute__((ext_vector_type(4)));
typedef float f32x4 __attribute__((ext_vector_type(4)));

#define B_ 2
#define C_ 512
#define HW_ 2304
#define GROUPS_ 32
#define CPG_ 16
#define EPS_ 1e-5f
#define THR_ 8.0f            // log2 units
#define LOG2E_ 1.44269504f
#define EXP2(x) __builtin_amdgcn_exp2f(x)

// async global->LDS, 16B per lane; LDS dest linear in lane order.
__device__ __forceinline__ void gload_lds16(const bf16* g, bf16* l) {
  __builtin_amdgcn_global_load_lds((const __attribute__((address_space(1))) void*)g,
                                   (__attribute__((address_space(3))) void*)l, 16, 0, 0);
}

// -------------------------------- fused: gn partial stats + weight prep
__global__ __launch_bounds__(256) void pre_k(const float* __restrict__ x,
                                             const float* __restrict__ qkv_w,
                                             const float* __restrict__ qkv_b,
                                             const float* __restrict__ proj_w,
                                             float* __restrict__ ps,
                                             float* __restrict__ pss,
                                             bf16* __restrict__ wqkv,
                                             bf16* __restrict__ wp,
                                             float* __restrict__ bqkv) {
  int blk = blockIdx.x;
  if (blk < 512) {
    int bg = blk >> 3, seg = blk & 7;
    const int n4 = CPG_ * HW_ / 4 / 8;  // 1152
    const float4* p = (const float4*)(x + (long)bg * CPG_ * HW_) + (long)seg * n4;
    float s = 0.f, ss = 0.f;
    for (int i = threadIdx.x; i < n4; i += 256) {
      float4 v = p[i];
      s += v.x + v.y + v.z + v.w;
      ss += v.x * v.x + v.y * v.y + v.z * v.z + v.w * v.w;
    }
#pragma unroll
    for (int d = 1; d < 64; d <<= 1) { s += __shfl_xor(s, d); ss += __shfl_xor(ss, d); }
    __shared__ float rs[4], rss[4];
    int wave = threadIdx.x >> 6, lane = threadIdx.x & 63;
    if (lane == 0) { rs[wave] = s; rss[wave] = ss; }
    __syncthreads();
    if (threadIdx.x == 0) {
      ps[blk] = rs[0] + rs[1] + rs[2] + rs[3];
      pss[blk] = rss[0] + rss[1] + rss[2] + rss[3];
    }
  } else {
    int idx = (blk - 512) * 256 + threadIdx.x;  // 0 .. 1536*512
    int r = idx >> 9, c = idx & 511;
    int src = (r < 512) ? 3 * r : (r < 1024 ? 3 * (r - 512) + 1 : 3 * (r - 1024) + 2);
    float sc = (r < 512) ? 0.125f * LOG2E_ : 1.0f;
    wqkv[idx] = (bf16)(qkv_w[(long)src * 512 + c] * sc);
    if (idx < 512 * 512) wp[idx] = (bf16)(proj_w[idx]);
    if (idx < 1536) {
      int sb = (idx < 512) ? 3 * idx : (idx < 1024 ? 3 * (idx - 512) + 1 : 3 * (idx - 1024) + 2);
      float sc2 = (idx < 512) ? 0.125f * LOG2E_ : 1.0f;
      bqkv[idx] = qkv_b[sb] * sc2;
    }
  }
}

// ------------------- gn apply + transpose->bf16 (finalizes stats inline)
__global__ __launch_bounds__(256) void gn_apply_k(const float* __restrict__ x,
                                                  const float* __restrict__ gw,
                                                  const float* __restrict__ gb,
                                                  const float* __restrict__ ps,
                                                  const float* __restrict__ pss,
                                                  bf16* __restrict__ xnT) {
  int n0 = blockIdx.x * 64, c0 = blockIdx.y * 32, b = blockIdx.z;
  int nn = n0 + (threadIdx.x & 63);
  int cb = c0 + ((threadIdx.x >> 6) << 3);
  __shared__ float smu[2], srstd[2];
  if (threadIdx.x < 2) {
    int gi = b * GROUPS_ + (c0 >> 4) + threadIdx.x;
    float s = 0.f, ss = 0.f;
#pragma unroll
    for (int k = 0; k < 8; ++k) { s += ps[gi * 8 + k]; ss += pss[gi * 8 + k]; }
    const float invN = 1.0f / (float)(CPG_ * HW_);
    float mu = s * invN;
    float var = ss * invN - mu * mu;
    smu[threadIdx.x] = mu;
    srstd[threadIdx.x] = rsqrtf(var + EPS_);
  }
  __syncthreads();
  int gsel = threadIdx.x >> 7;
  float mu = smu[gsel], rstd = srstd[gsel];
  bf16x8 o;
#pragma unroll
  for (int j = 0; j < 8; ++j) {
    int c = cb + j;
    float sc = rstd * gw[c];
    float sh = gb[c] - mu * sc;
    float v = x[((long)b * C_ + c) * HW_ + nn];
    o[j] = (bf16)(v * sc + sh);
  }
  *(bf16x8*)&xnT[((long)b * HW_ + nn) * C_ + cb] = o;
}

// --------------------------------------- fused QKV(+V^T) GEMM 128x64, 8 waves
// (verified r16) C[n][r] = xnT @ wqkv^T + bqkv. Cols <1024 (q,k) -> yT;
// cols >=1024 (v) -> transposed store into v[ch][n].
__global__ __launch_bounds__(512) void gemm_qkv_k(const bf16* __restrict__ A,
                                                  const bf16* __restrict__ BT,
                                                  const float* __restrict__ bias,
                                                  bf16* __restrict__ yT,
                                                  bf16* __restrict__ vOut) {
  constexpr int KK = 512;
  constexpr int NSTEP = KK >> 6;  // 8
  int b = blockIdx.z;
  A += (long)HW_ * 512 * b;
  yT += (long)HW_ * 1024 * b;
  vOut += (long)512 * HW_ * b;
  int m0 = blockIdx.y * 128, n0 = blockIdx.x * 64;
  int tid = threadIdx.x, lane = tid & 63, wave = tid >> 6;
  int wm = (wave >> 1) << 5, wn = (wave & 1) << 5;
  int fr = lane & 15, g = lane >> 4;
  __shared__ __align__(16) bf16 As[3][128 * 64];
  __shared__ __align__(16) bf16 Bs[3][64 * 64];
  int sr = tid >> 3;
  int swz = (((tid & 7) + sr) & 7) << 3;
  const bf16* gA = A + (long)(m0 + sr) * KK + swz;
  const bf16* gA2 = A + (long)(m0 + 64 + sr) * KK + swz;
  const bf16* gB = BT + (long)(n0 + sr) * KK + swz;
  int o0 = ((g - fr) & 7) << 3;
  int o1 = ((4 + g - fr) & 7) << 3;
  f32x4 acc[2][2] = {};
  gload_lds16(gA, &As[0][tid * 8]);
  gload_lds16(gA2, &As[0][4096 + tid * 8]);
  gload_lds16(gB, &Bs[0][tid * 8]);
  gload_lds16(gA + 64, &As[1][tid * 8]);
  gload_lds16(gA2 + 64, &As[1][4096 + tid * 8]);
  gload_lds16(gB + 64, &Bs[1][tid * 8]);
  asm volatile("s_waitcnt vmcnt(3)" ::: "memory");
  __builtin_amdgcn_s_barrier();
#pragma unroll
  for (int t = 0; t < NSTEP; ++t) {
    const int cur = t % 3;
    if (t + 2 < NSTEP) {
      const int nb = (t + 2) % 3;
      int k0 = (t + 2) << 6;
      gload_lds16(gA + k0, &As[nb][tid * 8]);
      gload_lds16(gA2 + k0, &As[nb][4096 + tid * 8]);
      gload_lds16(gB + k0, &Bs[nb][tid * 8]);
    }
    bf16x8 a00 = *(bf16x8*)&As[cur][(wm + fr) * 64 + o0];
    bf16x8 a01 = *(bf16x8*)&As[cur][(wm + fr) * 64 + o1];
    bf16x8 a10 = *(bf16x8*)&As[cur][(wm + 16 + fr) * 64 + o0];
    bf16x8 a11 = *(bf16x8*)&As[cur][(wm + 16 + fr) * 64 + o1];
    bf16x8 b00 = *(bf16x8*)&Bs[cur][(wn + fr) * 64 + o0];
    bf16x8 b01 = *(bf16x8*)&Bs[cur][(wn + fr) * 64 + o1];
    bf16x8 b10 = *(bf16x8*)&Bs[cur][(wn + 16 + fr) * 64 + o0];
    bf16x8 b11 = *(bf16x8*)&Bs[cur][(wn + 16 + fr) * 64 + o1];
    acc[0][0] = __builtin_amdgcn_mfma_f32_16x16x32_bf16(a00, b00, acc[0][0], 0, 0, 0);
    acc[0][0] = __builtin_amdgcn_mfma_f32_16x16x32_bf16(a01, b01, acc[0][0], 0, 0, 0);
    acc[0][1] = __builtin_amdgcn_mfma_f32_16x16x32_bf16(a00, b10, acc[0][1], 0, 0, 0);
    acc[0][1] = __builtin_amdgcn_mfma_f32_16x16x32_bf16(a01, b11, acc[0][1], 0, 0, 0);
    acc[1][0] = __builtin_amdgcn_mfma_f32_16x16x32_bf16(a10, b00, acc[1][0], 0, 0, 0);
    acc[1][0] = __builtin_amdgcn_mfma_f32_16x16x32_bf16(a11, b01, acc[1][0], 0, 0, 0);
    acc[1][1] = __builtin_amdgcn_mfma_f32_16x16x32_bf16(a10, b10, acc[1][1], 0, 0, 0);
    acc[1][1] = __builtin_amdgcn_mfma_f32_16x16x32_bf16(a11, b11, acc[1][1], 0, 0, 0);
    if (t + 2 < NSTEP) {
      asm volatile("s_waitcnt vmcnt(3) lgkmcnt(0)" ::: "memory");
    } else if (t + 1 < NSTEP) {
      asm volatile("s_waitcnt vmcnt(0) lgkmcnt(0)" ::: "memory");
    }
    if (t + 1 < NSTEP) __builtin_amdgcn_s_barrier();
  }
  int rbase = (lane >> 4) << 2;
  if (n0 < 1024) {
#pragma unroll
    for (int mi = 0; mi < 2; ++mi)
#pragma unroll
      for (int nj = 0; nj < 2; ++nj)
#pragma unroll
        for (int reg = 0; reg < 4; ++reg) {
          int row = m0 + wm + (mi << 4) + rbase + reg;
          int col = n0 + wn + (nj << 4) + fr;
          yT[(long)row * 1024 + col] = (bf16)(acc[mi][nj][reg] + bias[col]);
        }
  } else {
#pragma unroll
    for (int mi = 0; mi < 2; ++mi)
#pragma unroll
      for (int nj = 0; nj < 2; ++nj) {
        int row0 = m0 + wm + (mi << 4) + rbase;
        int ch = n0 - 1024 + wn + (nj << 4) + fr;
        float bs = bias[n0 + wn + (nj << 4) + fr];
        bf16x4 ov = {(bf16)(acc[mi][nj][0] + bs), (bf16)(acc[mi][nj][1] + bs),
                     (bf16)(acc[mi][nj][2] + bs), (bf16)(acc[mi][nj][3] + bs)};
        *(bf16x4*)&vOut[(long)ch * HW_ + row0] = ov;
      }
  }
}

// ---------------------------------------- proj GEMM 128x64, 8 waves
// out[o][n] = wp @ aT^T + proj_b + x. Same pipeline as gemm_qkv_k.
__global__ __launch_bounds__(512) void gemm_proj_k(const bf16* __restrict__ A,
                                                   const bf16* __restrict__ BT,
                                                   const float* __restrict__ bias,
                                                   const float* __restrict__ resid,
                                                   float* __restrict__ Cc) {
  constexpr int KK = 512;
  constexpr int NSTEP = KK >> 6;  // 8
  int b = blockIdx.z;
  BT += (long)HW_ * 512 * b;
  const float* R = resid + (long)512 * HW_ * b;
  Cc += (long)512 * HW_ * b;
  int m0 = blockIdx.y * 128, n0 = blockIdx.x * 64;
  int tid = threadIdx.x, lane = tid & 63, wave = tid >> 6;
  int wm = (wave >> 1) << 5, wn = (wave & 1) << 5;
  int fr = lane & 15, g = lane >> 4;
  __shared__ __align__(16) bf16 As[3][128 * 64];
  __shared__ __align__(16) bf16 Bs[3][64 * 64];
  int sr = tid >> 3;
  int swz = (((tid & 7) + sr) & 7) << 3;
  const bf16* gA = A + (long)(m0 + sr) * KK + swz;
  const bf16* gA2 = A + (long)(m0 + 64 + sr) * KK + swz;
  const bf16* gB = BT + (long)(n0 + sr) * KK + swz;
  int o0 = ((g - fr) & 7) << 3;
  int o1 = ((4 + g - fr) & 7) << 3;
  f32x4 acc[2][2] = {};
  gload_lds16(gA, &As[0][tid * 8]);
  gload_lds16(gA2, &As[0][4096 + tid * 8]);
  gload_lds16(gB, &Bs[0][tid * 8]);
  gload_lds16(gA + 64, &As[1][tid * 8]);
  gload_lds16(gA2 + 64, &As[1][4096 + tid * 8]);
  gload_lds16(gB + 64, &Bs[1][tid * 8]);
  asm volatile("s_waitcnt vmcnt(3)" ::: "memory");
  __builtin_amdgcn_s_barrier();
#pragma unroll
  for (int t = 0; t < NSTEP; ++t) {
    const int cur = t % 3;
    if (t + 2 < NSTEP) {
      const int nb = (t + 2) % 3;
      int k0 = (t + 2) << 6;
      gload_lds16(gA + k0, &As[nb][tid * 8]);
      gload_lds16(gA2 + k0, &As[nb][4096 + tid * 8]);
      gload_lds16(gB + k0, &Bs[nb][tid * 8]);
    }
    bf16x8 a00 = *(bf16x8*)&As[cur][(wm + fr) * 64 + o0];
    bf16x8 a01 = *(bf16x8*)&As[cur][(wm + fr) * 64 + o1];
    bf16x8 a10 = *(bf16x8*)&As[cur][(wm + 16 + fr) * 64 + o0];
    bf16x8 a11 = *(bf16x8*)&As[cur][(wm + 16 + fr) * 64 + o1];
    bf16x8 b00 = *(bf16x8*)&Bs[cur][(wn + fr) * 64 + o0];
    bf16x8 b01 = *(bf16x8*)&Bs[cur][(wn + fr) * 64 + o1];
    bf16x8 b10 = *(bf16x8*)&Bs[cur][(wn + 16 + fr) * 64 + o0];
    bf16x8 b11 = *(bf16x8*)&Bs[cur][(wn + 16 + fr) * 64 + o1];
    acc[0][0] = __builtin_amdgcn_mfma_f32_16x16x32_bf16(a00, b00, acc[0][0], 0, 0, 0);
    acc[0][0] = __builtin_amdgcn_mfma_f32_16x16x32_bf16(a01, b01, acc[0][0], 0, 0, 0);
    acc[0][1] = __builtin_amdgcn_mfma_f32_16x16x32_bf16(a00, b10, acc[0][1], 0, 0, 0);
    acc[0][1] = __builtin_amdgcn_mfma_f32_16x16x32_bf16(a01, b11, acc[0][1], 0, 0, 0);
    acc[1][0] = __builtin_amdgcn_mfma_f32_16x16x32_bf16(a10, b00, acc[1][0], 0, 0, 0);
    acc[1][0] = __builtin_amdgcn_mfma_f32_16x16x32_bf16(a11, b01, acc[1][0], 0, 0, 0);
    acc[1][1] = __builtin_amdgcn_mfma_f32_16x16x32_bf16(a10, b10, acc[1][1], 0, 0, 0);
    acc[1][1] = __builtin_amdgcn_mfma_f32_16x16x32_bf16(a11, b11, acc[1][1], 0, 0, 0);
    if (t + 2 < NSTEP) {
      asm volatile("s_waitcnt vmcnt(3) lgkmcnt(0)" ::: "memory");
    } else if (t + 1 < NSTEP) {
      asm volatile("s_waitcnt vmcnt(0) lgkmcnt(0)" ::: "memory");
    }
    if (t + 1 < NSTEP) __builtin_amdgcn_s_barrier();
  }
  int rbase = (lane >> 4) << 2;
#pragma unroll
  for (int mi = 0; mi < 2; ++mi)
#pragma unroll
    for (int nj = 0; nj < 2; ++nj)
#pragma unroll
      for (int reg = 0; reg < 4; ++reg) {
        int row = m0 + wm + (mi << 4) + rbase + reg;
        int col = n0 + wn + (nj << 4) + fr;
        Cc[(long)row * HW_ + col] =
            acc[mi][nj][reg] + bias[row] + R[(long)row * HW_ + col];
      }
}

// ------------------------------------------------------------- attention
// (verified r9/r13/r15) swapped-operand flash attention, 8 waves, NS-way split.
template <int NS>
__global__ __launch_bounds__(512) void attn_k(const bf16* __restrict__ yT,
                                              const bf16* __restrict__ V,
                                              bf16* __restrict__ Op,
                                              float* __restrict__ Mp,
                                              float* __restrict__ Lp) {
  const int n = HW_;
  constexpr int NT = (HW_ / NS) / 64;
  int bh = blockIdx.y, b = bh >> 3, h = bh & 7;
  int split = blockIdx.z;
  int q0 = blockIdx.x * 128;
  int kbeg = split * (n / NS);
  int tid = threadIdx.x, lane = tid & 63, wave = tid >> 6;
  int fr = lane & 15, g = lane >> 4, kg = g << 3;
  const bf16* yTb = yT + (long)b * n * 1024;
  const bf16* Vb = V + ((long)b * C_ + h * 64) * n;
  const bf16* Kb = yTb + 512 + h * 64;

  int qrow = q0 + (wave << 4) + fr;
  const bf16* qp = yTb + (long)qrow * 1024 + h * 64;
  bf16x8 qf0 = *(const bf16x8*)(qp + kg);
  bf16x8 qf1 = *(const bf16x8*)(qp + 32 + kg);

  __shared__ __align__(16) bf16 Kt[2][64][64];
  __shared__ __align__(16) bf16 Vt[2][64][64];

  int o0 = ((g + fr) & 7) << 3;
  int o1 = ((4 + g + fr) & 7) << 3;

  float m_run = -1e30f, l_run = 0.f;
  f32x4 oacc[4] = {};

  int r0 = tid >> 3;
  int ck = tid & 7;
  int c0e = ck << 3;
  int pk = ((ck + r0) & 7) << 3;
  int vs = (c0e & 32) | ((c0e & 8) << 1) | ((c0e & 16) >> 2);
  int cv = vs >> 3, sub = vs & 7;
  int pv0 = (((cv + r0) & 7) << 3) + sub;
  int pv1 = (((cv + 1 + r0) & 7) << 3) + sub;

  const bf16* kptr = Kb + (long)(kbeg + r0) * 1024 + c0e;
  const bf16* vptr = Vb + (long)r0 * n + kbeg + c0e;
  uint4 rk = *(const uint4*)kptr;
  uint4 rv = *(const uint4*)vptr;
  *(uint4*)&Kt[0][r0][pk] = rk;
  *(uint2*)&Vt[0][r0][pv0] = make_uint2(rv.x, rv.y);
  *(uint2*)&Vt[0][r0][pv1] = make_uint2(rv.z, rv.w);
  kptr += 64 * 1024;
  vptr += 64;
  rk = *(const uint4*)kptr;
  rv = *(const uint4*)vptr;
  __syncthreads();

  for (int t = 0; t < NT; ++t) {
    int cur = t & 1;
    f32x4 s[4] = {};
    __builtin_amdgcn_s_setprio(1);
#pragma unroll
    for (int nj = 0; nj < 4; ++nj) {
      bf16x8 kf0 = *(bf16x8*)&Kt[cur][(nj << 4) + fr][o0];
      bf16x8 kf1 = *(bf16x8*)&Kt[cur][(nj << 4) + fr][o1];
      s[nj] = __builtin_amdgcn_mfma_f32_16x16x32_bf16(kf0, qf0, s[nj], 0, 0, 0);
      s[nj] = __builtin_amdgcn_mfma_f32_16x16x32_bf16(kf1, qf1, s[nj], 0, 0, 0);
    }
    __builtin_amdgcn_s_setprio(0);
    if (t + 1 < NT) {
      int nb = cur ^ 1;
      *(uint4*)&Kt[nb][r0][pk] = rk;
      *(uint2*)&Vt[nb][r0][pv0] = make_uint2(rv.x, rv.y);
      *(uint2*)&Vt[nb][r0][pv1] = make_uint2(rv.z, rv.w);
      if (t + 2 < NT) {
        kptr += 64 * 1024;
        vptr += 64;
        rk = *(const uint4*)kptr;
        rv = *(const uint4*)vptr;
      }
    }
    float pm = fmaxf(fmaxf(s[0][0], s[0][1]), fmaxf(s[0][2], s[0][3]));
#pragma unroll
    for (int nj = 1; nj < 4; ++nj)
      pm = fmaxf(pm, fmaxf(fmaxf(s[nj][0], s[nj][1]), fmaxf(s[nj][2], s[nj][3])));
    pm = fmaxf(pm, __shfl_xor(pm, 16));
    pm = fmaxf(pm, __shfl_xor(pm, 32));
    if (__any(pm > m_run + THR_)) {
      float mn = fmaxf(m_run, pm);
      float corr = EXP2(m_run - mn);
      m_run = mn;
      l_run *= corr;
#pragma unroll
      for (int dj = 0; dj < 4; ++dj)
#pragma unroll
        for (int r = 0; r < 4; ++r) oacc[dj][r] *= corr;
    }
    float ls = 0.f;
    bf16x8 pa0, pa1;
#pragma unroll
    for (int r = 0; r < 4; ++r) {
      float p0 = EXP2(s[0][r] - m_run);
      float p1 = EXP2(s[1][r] - m_run);
      float p2 = EXP2(s[2][r] - m_run);
      float p3 = EXP2(s[3][r] - m_run);
      ls += (p0 + p1) + (p2 + p3);
      pa0[r] = (bf16)p0;
      pa0[4 + r] = (bf16)p1;
      pa1[r] = (bf16)p2;
      pa1[4 + r] = (bf16)p3;
    }
    ls += __shfl_xor(ls, 16);
    ls += __shfl_xor(ls, 32);
    l_run += ls;
    __builtin_amdgcn_s_setprio(1);
#pragma unroll
    for (int dj = 0; dj < 4; ++dj) {
      bf16x8 vf0 = *(bf16x8*)&Vt[cur][(dj << 4) + fr][o0];
      bf16x8 vf1 = *(bf16x8*)&Vt[cur][(dj << 4) + fr][o1];
      oacc[dj] = __builtin_amdgcn_mfma_f32_16x16x32_bf16(vf0, pa0, oacc[dj], 0, 0, 0);
      oacc[dj] = __builtin_amdgcn_mfma_f32_16x16x32_bf16(vf1, pa1, oacc[dj], 0, 0, 0);
    }
    __builtin_amdgcn_s_setprio(0);
    __syncthreads();
  }
  long orow = (long)(split * 16 + bh) * n + q0 + (wave << 4) + fr;
#pragma unroll
  for (int dj = 0; dj < 4; ++dj) {
    bf16x4 ov = {(bf16)oacc[dj][0], (bf16)oacc[dj][1], (bf16)oacc[dj][2], (bf16)oacc[dj][3]};
    *(bf16x4*)&Op[orow * 64 + (dj << 4) + (g << 2)] = ov;
  }
  if (g == 0) {
    Mp[orow] = m_run;
    Lp[orow] = l_run;
  }
}

// ----------------------------------------------------------- split merge
template <int NS>
__global__ __launch_bounds__(256) void attn_merge_k(const bf16* __restrict__ Op,
                                                    const float* __restrict__ Mp,
                                                    const float* __restrict__ Lp,
                                                    bf16* __restrict__ aT) {
  int bh = blockIdx.y, b = bh >> 3, h = bh & 7;
  int gi = blockIdx.x * 256 + threadIdx.x;
  int nrow = gi >> 3, dd8 = (gi & 7) << 3;
  long idx[NS];
  float mm = -1e30f;
#pragma unroll
  for (int s = 0; s < NS; ++s) {
    idx[s] = (long)(s * 16 + bh) * HW_ + nrow;
    mm = fmaxf(mm, Mp[idx[s]]);
  }
  float l = 0.f, w[NS];
#pragma unroll
  for (int s = 0; s < NS; ++s) {
    w[s] = EXP2(Mp[idx[s]] - mm);
    l += Lp[idx[s]] * w[s];
  }
  float invl = 1.f / l;
  float oaccf[8] = {};
#pragma unroll
  for (int s = 0; s < NS; ++s) {
    bf16x8 o = *(const bf16x8*)&Op[idx[s] * 64 + dd8];
    float ws = w[s] * invl;
#pragma unroll
    for (int j = 0; j < 8; ++j) oaccf[j] += (float)o[j] * ws;
  }
  bf16x8 o;
#pragma unroll
  for (int j = 0; j < 8; ++j) o[j] = (bf16)oaccf[j];
  *(bf16x8*)&aT[((long)b * HW_ + nrow) * C_ + h * 64 + dd8] = o;
}

// ----------------------------------------------------------------- launch
extern "C" void kernel_launch(void* const* d_in, const int* in_sizes, int n_in,
                              void* d_out, int out_size, void* d_ws, size_t ws_size,
                              hipStream_t stream) {
  const float* x = (const float*)d_in[0];
  const float* gn_w = (const float*)d_in[1];
  const float* gn_b = (const float*)d_in[2];
  const float* qkv_w = (const float*)d_in[3];
  const float* qkv_b = (const float*)d_in[4];
  const float* proj_w = (const float*)d_in[5];
  const float* proj_b = (const float*)d_in[6];
  float* out = (float*)d_out;

  char* ws = (char*)d_ws;
  float* ps = (float*)ws;    ws += 2048;
  float* pss = (float*)ws;   ws += 2048;
  float* bqkv = (float*)ws;  ws += 6144;
  bf16* wqkv = (bf16*)ws;    ws += 1536l * 512 * 2;
  bf16* wp = (bf16*)ws;      ws += 512l * 512 * 2;
  bf16* xnT = (bf16*)ws;     ws += 2l * HW_ * 512 * 2;
  bf16* yT = (bf16*)ws;      ws += 2l * HW_ * 1024 * 2;
  bf16* v = (bf16*)ws;       ws += 2l * 512 * HW_ * 2;
  bf16* aT = (bf16*)ws;      ws += 2l * HW_ * 512 * 2;
  bf16* Op = (bf16*)ws;      // NS*16*HW*64 bf16
  size_t base_used = (size_t)(ws - (char*)d_ws);
  size_t need4 = base_used + 4ull * 16 * HW_ * 64 * 2 + 2ull * 4 * 16 * HW_ * 4;
  int NS = (ws_size >= need4) ? 4 : 2;
  ws += (size_t)NS * 16 * HW_ * 64 * 2;
  float* Mp = (float*)ws;    ws += (size_t)NS * 16 * HW_ * 4;
  float* Lp = (float*)ws;    ws += (size_t)NS * 16 * HW_ * 4;

  pre_k<<<3584, 256, 0, stream>>>(x, qkv_w, qkv_b, proj_w, ps, pss, wqkv, wp, bqkv);
  gn_apply_k<<<dim3(36, 16, 2), 256, 0, stream>>>(x, gn_w, gn_b, ps, pss, xnT);
  // fused: yT[n][0:1024) (q,k) + v[ch][n] transposed  (M=2304, N=1536, K=512)
  gemm_qkv_k<<<dim3(24, 18, 2), 512, 0, stream>>>(xnT, wqkv, bqkv, yT, v);
  if (NS == 4) {
    attn_k<4><<<dim3(18, 16, 4), 512, 0, stream>>>(yT, v, Op, Mp, Lp);
    attn_merge_k<4><<<dim3(72, 16), 256, 0, stream>>>(Op, Mp, Lp, aT);
  } else {
    attn_k<2><<<dim3(18, 16, 2), 512, 0, stream>>>(yT, v, Op, Mp, Lp);
    attn_merge_k<2><<<dim3(72, 16), 256, 0, stream>>>(Op, Mp, Lp, aT);
  }
  // out = wp @ aT^T + proj_b + x  (M=512, N=2304, K=512), fp32 out
  gemm_proj_k<<<dim3(36, 4, 2), 512, 0, stream>>>(wp, aT, proj_b, x, out);
}

// Round 18
// 83.783 us; speedup vs baseline: 1.0117x; 1.0117x over previous
//
#include <hip/hip_runtime.h>

typedef __bf16 bf16;
typedef __bf16 bf16x8 __attribute__((ext_vector_type(8)));
typedef __bf16 bf16x4 __attribute__((ext_vector_type(4)));
typedef float f32x4 __attribute__((ext_vector_type(4)));

#define B_ 2
#define C_ 512
#define HW_ 2304
#define GROUPS_ 32
#define CPG_ 16
#define EPS_ 1e-5f
#define THR_ 8.0f            // log2 units
#define LOG2E_ 1.44269504f
#define EXP2(x) __builtin_amdgcn_exp2f(x)

// async global->LDS, 16B per lane; LDS dest linear in lane order.
__device__ __forceinline__ void gload_lds16(const bf16* g, bf16* l) {
  __builtin_amdgcn_global_load_lds((const __attribute__((address_space(1))) void*)g,
                                   (__attribute__((address_space(3))) void*)l, 16, 0, 0);
}

// -------------------------------- fused: gn partial stats + weight prep
__global__ __launch_bounds__(256) void pre_k(const float* __restrict__ x,
                                             const float* __restrict__ qkv_w,
                                             const float* __restrict__ qkv_b,
                                             const float* __restrict__ proj_w,
                                             float* __restrict__ ps,
                                             float* __restrict__ pss,
                                             bf16* __restrict__ wqkv,
                                             bf16* __restrict__ wp,
                                             float* __restrict__ bqkv) {
  int blk = blockIdx.x;
  if (blk < 512) {
    int bg = blk >> 3, seg = blk & 7;
    const int n4 = CPG_ * HW_ / 4 / 8;  // 1152
    const float4* p = (const float4*)(x + (long)bg * CPG_ * HW_) + (long)seg * n4;
    float s = 0.f, ss = 0.f;
    for (int i = threadIdx.x; i < n4; i += 256) {
      float4 v = p[i];
      s += v.x + v.y + v.z + v.w;
      ss += v.x * v.x + v.y * v.y + v.z * v.z + v.w * v.w;
    }
#pragma unroll
    for (int d = 1; d < 64; d <<= 1) { s += __shfl_xor(s, d); ss += __shfl_xor(ss, d); }
    __shared__ float rs[4], rss[4];
    int wave = threadIdx.x >> 6, lane = threadIdx.x & 63;
    if (lane == 0) { rs[wave] = s; rss[wave] = ss; }
    __syncthreads();
    if (threadIdx.x == 0) {
      ps[blk] = rs[0] + rs[1] + rs[2] + rs[3];
      pss[blk] = rss[0] + rss[1] + rss[2] + rss[3];
    }
  } else {
    int idx = (blk - 512) * 256 + threadIdx.x;  // 0 .. 1536*512
    int r = idx >> 9, c = idx & 511;
    int src = (r < 512) ? 3 * r : (r < 1024 ? 3 * (r - 512) + 1 : 3 * (r - 1024) + 2);
    float sc = (r < 512) ? 0.125f * LOG2E_ : 1.0f;
    wqkv[idx] = (bf16)(qkv_w[(long)src * 512 + c] * sc);
    if (idx < 512 * 512) wp[idx] = (bf16)(proj_w[idx]);
    if (idx < 1536) {
      int sb = (idx < 512) ? 3 * idx : (idx < 1024 ? 3 * (idx - 512) + 1 : 3 * (idx - 1024) + 2);
      float sc2 = (idx < 512) ? 0.125f * LOG2E_ : 1.0f;
      bqkv[idx] = qkv_b[sb] * sc2;
    }
  }
}

// ------------------- gn apply + transpose->bf16 (finalizes stats inline)
__global__ __launch_bounds__(256) void gn_apply_k(const float* __restrict__ x,
                                                  const float* __restrict__ gw,
                                                  const float* __restrict__ gb,
                                                  const float* __restrict__ ps,
                                                  const float* __restrict__ pss,
                                                  bf16* __restrict__ xnT) {
  int n0 = blockIdx.x * 64, c0 = blockIdx.y * 32, b = blockIdx.z;
  int nn = n0 + (threadIdx.x & 63);
  int cb = c0 + ((threadIdx.x >> 6) << 3);
  __shared__ float smu[2], srstd[2];
  if (threadIdx.x < 2) {
    int gi = b * GROUPS_ + (c0 >> 4) + threadIdx.x;
    float s = 0.f, ss = 0.f;
#pragma unroll
    for (int k = 0; k < 8; ++k) { s += ps[gi * 8 + k]; ss += pss[gi * 8 + k]; }
    const float invN = 1.0f / (float)(CPG_ * HW_);
    float mu = s * invN;
    float var = ss * invN - mu * mu;
    smu[threadIdx.x] = mu;
    srstd[threadIdx.x] = rsqrtf(var + EPS_);
  }
  __syncthreads();
  int gsel = threadIdx.x >> 7;
  float mu = smu[gsel], rstd = srstd[gsel];
  bf16x8 o;
#pragma unroll
  for (int j = 0; j < 8; ++j) {
    int c = cb + j;
    float sc = rstd * gw[c];
    float sh = gb[c] - mu * sc;
    float v = x[((long)b * C_ + c) * HW_ + nn];
    o[j] = (bf16)(v * sc + sh);
  }
  *(bf16x8*)&xnT[((long)b * HW_ + nn) * C_ + cb] = o;
}

// --------------------------------------- fused QKV(+V^T) GEMM 128x64, 8 waves
// (verified r16) C[n][r] = xnT @ wqkv^T + bqkv. Cols <1024 (q,k) -> yT;
// cols >=1024 (v) -> transposed store into v[ch][n].
__global__ __launch_bounds__(512) void gemm_qkv_k(const bf16* __restrict__ A,
                                                  const bf16* __restrict__ BT,
                                                  const float* __restrict__ bias,
                                                  bf16* __restrict__ yT,
                                                  bf16* __restrict__ vOut) {
  constexpr int KK = 512;
  constexpr int NSTEP = KK >> 6;  // 8
  int b = blockIdx.z;
  A += (long)HW_ * 512 * b;
  yT += (long)HW_ * 1024 * b;
  vOut += (long)512 * HW_ * b;
  int m0 = blockIdx.y * 128, n0 = blockIdx.x * 64;
  int tid = threadIdx.x, lane = tid & 63, wave = tid >> 6;
  int wm = (wave >> 1) << 5, wn = (wave & 1) << 5;
  int fr = lane & 15, g = lane >> 4;
  __shared__ __align__(16) bf16 As[3][128 * 64];
  __shared__ __align__(16) bf16 Bs[3][64 * 64];
  int sr = tid >> 3;
  int swz = (((tid & 7) + sr) & 7) << 3;
  const bf16* gA = A + (long)(m0 + sr) * KK + swz;
  const bf16* gA2 = A + (long)(m0 + 64 + sr) * KK + swz;
  const bf16* gB = BT + (long)(n0 + sr) * KK + swz;
  int o0 = ((g - fr) & 7) << 3;
  int o1 = ((4 + g - fr) & 7) << 3;
  f32x4 acc[2][2] = {};
  gload_lds16(gA, &As[0][tid * 8]);
  gload_lds16(gA2, &As[0][4096 + tid * 8]);
  gload_lds16(gB, &Bs[0][tid * 8]);
  gload_lds16(gA + 64, &As[1][tid * 8]);
  gload_lds16(gA2 + 64, &As[1][4096 + tid * 8]);
  gload_lds16(gB + 64, &Bs[1][tid * 8]);
  asm volatile("s_waitcnt vmcnt(3)" ::: "memory");
  __builtin_amdgcn_s_barrier();
#pragma unroll
  for (int t = 0; t < NSTEP; ++t) {
    const int cur = t % 3;
    if (t + 2 < NSTEP) {
      const int nb = (t + 2) % 3;
      int k0 = (t + 2) << 6;
      gload_lds16(gA + k0, &As[nb][tid * 8]);
      gload_lds16(gA2 + k0, &As[nb][4096 + tid * 8]);
      gload_lds16(gB + k0, &Bs[nb][tid * 8]);
    }
    bf16x8 a00 = *(bf16x8*)&As[cur][(wm + fr) * 64 + o0];
    bf16x8 a01 = *(bf16x8*)&As[cur][(wm + fr) * 64 + o1];
    bf16x8 a10 = *(bf16x8*)&As[cur][(wm + 16 + fr) * 64 + o0];
    bf16x8 a11 = *(bf16x8*)&As[cur][(wm + 16 + fr) * 64 + o1];
    bf16x8 b00 = *(bf16x8*)&Bs[cur][(wn + fr) * 64 + o0];
    bf16x8 b01 = *(bf16x8*)&Bs[cur][(wn + fr) * 64 + o1];
    bf16x8 b10 = *(bf16x8*)&Bs[cur][(wn + 16 + fr) * 64 + o0];
    bf16x8 b11 = *(bf16x8*)&Bs[cur][(wn + 16 + fr) * 64 + o1];
    acc[0][0] = __builtin_amdgcn_mfma_f32_16x16x32_bf16(a00, b00, acc[0][0], 0, 0, 0);
    acc[0][0] = __builtin_amdgcn_mfma_f32_16x16x32_bf16(a01, b01, acc[0][0], 0, 0, 0);
    acc[0][1] = __builtin_amdgcn_mfma_f32_16x16x32_bf16(a00, b10, acc[0][1], 0, 0, 0);
    acc[0][1] = __builtin_amdgcn_mfma_f32_16x16x32_bf16(a01, b11, acc[0][1], 0, 0, 0);
    acc[1][0] = __builtin_amdgcn_mfma_f32_16x16x32_bf16(a10, b00, acc[1][0], 0, 0, 0);
    acc[1][0] = __builtin_amdgcn_mfma_f32_16x16x32_bf16(a11, b01, acc[1][0], 0, 0, 0);
    acc[1][1] = __builtin_amdgcn_mfma_f32_16x16x32_bf16(a10, b10, acc[1][1], 0, 0, 0);
    acc[1][1] = __builtin_amdgcn_mfma_f32_16x16x32_bf16(a11, b11, acc[1][1], 0, 0, 0);
    if (t + 2 < NSTEP) {
      asm volatile("s_waitcnt vmcnt(3) lgkmcnt(0)" ::: "memory");
    } else if (t + 1 < NSTEP) {
      asm volatile("s_waitcnt vmcnt(0) lgkmcnt(0)" ::: "memory");
    }
    if (t + 1 < NSTEP) __builtin_amdgcn_s_barrier();
  }
  int rbase = (lane >> 4) << 2;
  if (n0 < 1024) {
#pragma unroll
    for (int mi = 0; mi < 2; ++mi)
#pragma unroll
      for (int nj = 0; nj < 2; ++nj)
#pragma unroll
        for (int reg = 0; reg < 4; ++reg) {
          int row = m0 + wm + (mi << 4) + rbase + reg;
          int col = n0 + wn + (nj << 4) + fr;
          yT[(long)row * 1024 + col] = (bf16)(acc[mi][nj][reg] + bias[col]);
        }
  } else {
#pragma unroll
    for (int mi = 0; mi < 2; ++mi)
#pragma unroll
      for (int nj = 0; nj < 2; ++nj) {
        int row0 = m0 + wm + (mi << 4) + rbase;
        int ch = n0 - 1024 + wn + (nj << 4) + fr;
        float bs = bias[n0 + wn + (nj << 4) + fr];
        bf16x4 ov = {(bf16)(acc[mi][nj][0] + bs), (bf16)(acc[mi][nj][1] + bs),
                     (bf16)(acc[mi][nj][2] + bs), (bf16)(acc[mi][nj][3] + bs)};
        *(bf16x4*)&vOut[(long)ch * HW_ + row0] = ov;
      }
  }
}

// ---------------------------------------- proj GEMM 128x64, 8 waves
// (verified r17) out[o][n] = wp @ aT^T + proj_b + x.
__global__ __launch_bounds__(512) void gemm_proj_k(const bf16* __restrict__ A,
                                                   const bf16* __restrict__ BT,
                                                   const float* __restrict__ bias,
                                                   const float* __restrict__ resid,
                                                   float* __restrict__ Cc) {
  constexpr int KK = 512;
  constexpr int NSTEP = KK >> 6;  // 8
  int b = blockIdx.z;
  BT += (long)HW_ * 512 * b;
  const float* R = resid + (long)512 * HW_ * b;
  Cc += (long)512 * HW_ * b;
  int m0 = blockIdx.y * 128, n0 = blockIdx.x * 64;
  int tid = threadIdx.x, lane = tid & 63, wave = tid >> 6;
  int wm = (wave >> 1) << 5, wn = (wave & 1) << 5;
  int fr = lane & 15, g = lane >> 4;
  __shared__ __align__(16) bf16 As[3][128 * 64];
  __shared__ __align__(16) bf16 Bs[3][64 * 64];
  int sr = tid >> 3;
  int swz = (((tid & 7) + sr) & 7) << 3;
  const bf16* gA = A + (long)(m0 + sr) * KK + swz;
  const bf16* gA2 = A + (long)(m0 + 64 + sr) * KK + swz;
  const bf16* gB = BT + (long)(n0 + sr) * KK + swz;
  int o0 = ((g - fr) & 7) << 3;
  int o1 = ((4 + g - fr) & 7) << 3;
  f32x4 acc[2][2] = {};
  gload_lds16(gA, &As[0][tid * 8]);
  gload_lds16(gA2, &As[0][4096 + tid * 8]);
  gload_lds16(gB, &Bs[0][tid * 8]);
  gload_lds16(gA + 64, &As[1][tid * 8]);
  gload_lds16(gA2 + 64, &As[1][4096 + tid * 8]);
  gload_lds16(gB + 64, &Bs[1][tid * 8]);
  asm volatile("s_waitcnt vmcnt(3)" ::: "memory");
  __builtin_amdgcn_s_barrier();
#pragma unroll
  for (int t = 0; t < NSTEP; ++t) {
    const int cur = t % 3;
    if (t + 2 < NSTEP) {
      const int nb = (t + 2) % 3;
      int k0 = (t + 2) << 6;
      gload_lds16(gA + k0, &As[nb][tid * 8]);
      gload_lds16(gA2 + k0, &As[nb][4096 + tid * 8]);
      gload_lds16(gB + k0, &Bs[nb][tid * 8]);
    }
    bf16x8 a00 = *(bf16x8*)&As[cur][(wm + fr) * 64 + o0];
    bf16x8 a01 = *(bf16x8*)&As[cur][(wm + fr) * 64 + o1];
    bf16x8 a10 = *(bf16x8*)&As[cur][(wm + 16 + fr) * 64 + o0];
    bf16x8 a11 = *(bf16x8*)&As[cur][(wm + 16 + fr) * 64 + o1];
    bf16x8 b00 = *(bf16x8*)&Bs[cur][(wn + fr) * 64 + o0];
    bf16x8 b01 = *(bf16x8*)&Bs[cur][(wn + fr) * 64 + o1];
    bf16x8 b10 = *(bf16x8*)&Bs[cur][(wn + 16 + fr) * 64 + o0];
    bf16x8 b11 = *(bf16x8*)&Bs[cur][(wn + 16 + fr) * 64 + o1];
    acc[0][0] = __builtin_amdgcn_mfma_f32_16x16x32_bf16(a00, b00, acc[0][0], 0, 0, 0);
    acc[0][0] = __builtin_amdgcn_mfma_f32_16x16x32_bf16(a01, b01, acc[0][0], 0, 0, 0);
    acc[0][1] = __builtin_amdgcn_mfma_f32_16x16x32_bf16(a00, b10, acc[0][1], 0, 0, 0);
    acc[0][1] = __builtin_amdgcn_mfma_f32_16x16x32_bf16(a01, b11, acc[0][1], 0, 0, 0);
    acc[1][0] = __builtin_amdgcn_mfma_f32_16x16x32_bf16(a10, b00, acc[1][0], 0, 0, 0);
    acc[1][0] = __builtin_amdgcn_mfma_f32_16x16x32_bf16(a11, b01, acc[1][0], 0, 0, 0);
    acc[1][1] = __builtin_amdgcn_mfma_f32_16x16x32_bf16(a10, b10, acc[1][1], 0, 0, 0);
    acc[1][1] = __builtin_amdgcn_mfma_f32_16x16x32_bf16(a11, b11, acc[1][1], 0, 0, 0);
    if (t + 2 < NSTEP) {
      asm volatile("s_waitcnt vmcnt(3) lgkmcnt(0)" ::: "memory");
    } else if (t + 1 < NSTEP) {
      asm volatile("s_waitcnt vmcnt(0) lgkmcnt(0)" ::: "memory");
    }
    if (t + 1 < NSTEP) __builtin_amdgcn_s_barrier();
  }
  int rbase = (lane >> 4) << 2;
#pragma unroll
  for (int mi = 0; mi < 2; ++mi)
#pragma unroll
    for (int nj = 0; nj < 2; ++nj)
#pragma unroll
      for (int reg = 0; reg < 4; ++reg) {
        int row = m0 + wm + (mi << 4) + rbase + reg;
        int col = n0 + wn + (nj << 4) + fr;
        Cc[(long)row * HW_ + col] =
            acc[mi][nj][reg] + bias[row] + R[(long)row * HW_ + col];
      }
}

// ------------------------------------------------------------- attention
// Paired-tile swapped-operand flash attention: 4 LDS buffers, tiles (2p,2p+1)
// processed per barrier with a JOINT max (math == one 128-key flash step).
// Barriers and rescales halved; QK/PV MFMA groups doubled in width for ILP.
// Staging algebra (pk/pv rotation+slot-perm) identical to verified r9/r15.
template <int NS>
__global__ __launch_bounds__(512) void attn_k(const bf16* __restrict__ yT,
                                              const bf16* __restrict__ V,
                                              bf16* __restrict__ Op,
                                              float* __restrict__ Mp,
                                              float* __restrict__ Lp) {
  const int n = HW_;
  constexpr int NT = (HW_ / NS) / 64;
  constexpr int NPAIR = NT / 2;
  constexpr int TAIL = NT & 1;
  int bh = blockIdx.y, b = bh >> 3, h = bh & 7;
  int split = blockIdx.z;
  int q0 = blockIdx.x * 128;
  int kbeg = split * (n / NS);
  int tid = threadIdx.x, lane = tid & 63, wave = tid >> 6;
  int fr = lane & 15, g = lane >> 4, kg = g << 3;
  const bf16* yTb = yT + (long)b * n * 1024;
  const bf16* Vb = V + ((long)b * C_ + h * 64) * n;
  const bf16* Kb = yTb + 512 + h * 64;

  int qrow = q0 + (wave << 4) + fr;
  const bf16* qp = yTb + (long)qrow * 1024 + h * 64;
  bf16x8 qf0 = *(const bf16x8*)(qp + kg);
  bf16x8 qf1 = *(const bf16x8*)(qp + 32 + kg);

  __shared__ __align__(16) bf16 Kt[4][64][64];
  __shared__ __align__(16) bf16 Vt[4][64][64];

  int o0 = ((g + fr) & 7) << 3;
  int o1 = ((4 + g + fr) & 7) << 3;

  float m_run = -1e30f, l_run = 0.f;
  f32x4 oacc[4] = {};

  int r0 = tid >> 3;
  int ck = tid & 7;
  int c0e = ck << 3;
  int pk = ((ck + r0) & 7) << 3;
  int vs = (c0e & 32) | ((c0e & 8) << 1) | ((c0e & 16) >> 2);
  int cv = vs >> 3, sub = vs & 7;
  int pv0 = (((cv + r0) & 7) << 3) + sub;
  int pv1 = (((cv + 1 + r0) & 7) << 3) + sub;

  const bf16* kbase = Kb + (long)(kbeg + r0) * 1024 + c0e;
  const bf16* vbase = Vb + (long)r0 * n + kbeg + c0e;

#define LDK_(t) (*(const uint4*)(kbase + (long)(t) * 64 * 1024))
#define LDV_(t) (*(const uint4*)(vbase + (t) * 64))
#define WRT_(t, rk, rv)                                          \
  {                                                              \
    *(uint4*)&Kt[(t) & 3][r0][pk] = (rk);                        \
    *(uint2*)&Vt[(t) & 3][r0][pv0] = make_uint2((rv).x, (rv).y); \
    *(uint2*)&Vt[(t) & 3][r0][pv1] = make_uint2((rv).z, (rv).w); \
  }

  uint4 rkA = LDK_(0), rvA = LDV_(0);
  uint4 rkB = LDK_(1), rvB = LDV_(1);
  WRT_(0, rkA, rvA);
  WRT_(1, rkB, rvB);
  if (2 < NT) { rkA = LDK_(2); rvA = LDV_(2); }
  if (3 < NT) { rkB = LDK_(3); rvB = LDV_(3); }
  __syncthreads();

#pragma unroll
  for (int p = 0; p < NPAIR; ++p) {
    const int tA = 2 * p, tB = tA + 1;
    const int bA = tA & 3, bB = tB & 3;
    f32x4 sA[4] = {}, sB[4] = {};
    __builtin_amdgcn_s_setprio(1);
#pragma unroll
    for (int nj = 0; nj < 4; ++nj) {
      bf16x8 kf0 = *(bf16x8*)&Kt[bA][(nj << 4) + fr][o0];
      bf16x8 kf1 = *(bf16x8*)&Kt[bA][(nj << 4) + fr][o1];
      sA[nj] = __builtin_amdgcn_mfma_f32_16x16x32_bf16(kf0, qf0, sA[nj], 0, 0, 0);
      sA[nj] = __builtin_amdgcn_mfma_f32_16x16x32_bf16(kf1, qf1, sA[nj], 0, 0, 0);
    }
#pragma unroll
    for (int nj = 0; nj < 4; ++nj) {
      bf16x8 kf0 = *(bf16x8*)&Kt[bB][(nj << 4) + fr][o0];
      bf16x8 kf1 = *(bf16x8*)&Kt[bB][(nj << 4) + fr][o1];
      sB[nj] = __builtin_amdgcn_mfma_f32_16x16x32_bf16(kf0, qf0, sB[nj], 0, 0, 0);
      sB[nj] = __builtin_amdgcn_mfma_f32_16x16x32_bf16(kf1, qf1, sB[nj], 0, 0, 0);
    }
    __builtin_amdgcn_s_setprio(0);
    // stage next pair (buffers not read this pair), prefetch pair after
    if (tA + 2 < NT) WRT_(tA + 2, rkA, rvA);
    if (tB + 2 < NT) WRT_(tB + 2, rkB, rvB);
    if (tA + 4 < NT) { rkA = LDK_(tA + 4); rvA = LDV_(tA + 4); }
    if (tB + 4 < NT) { rkB = LDK_(tB + 4); rvB = LDV_(tB + 4); }
    // joint online softmax over both tiles (== one 128-key flash step)
    float pm = fmaxf(fmaxf(sA[0][0], sA[0][1]), fmaxf(sA[0][2], sA[0][3]));
#pragma unroll
    for (int nj = 1; nj < 4; ++nj)
      pm = fmaxf(pm, fmaxf(fmaxf(sA[nj][0], sA[nj][1]), fmaxf(sA[nj][2], sA[nj][3])));
#pragma unroll
    for (int nj = 0; nj < 4; ++nj)
      pm = fmaxf(pm, fmaxf(fmaxf(sB[nj][0], sB[nj][1]), fmaxf(sB[nj][2], sB[nj][3])));
    pm = fmaxf(pm, __shfl_xor(pm, 16));
    pm = fmaxf(pm, __shfl_xor(pm, 32));
    if (__any(pm > m_run + THR_)) {
      float mn = fmaxf(m_run, pm);
      float corr = EXP2(m_run - mn);
      m_run = mn;
      l_run *= corr;
#pragma unroll
      for (int dj = 0; dj < 4; ++dj)
#pragma unroll
        for (int r = 0; r < 4; ++r) oacc[dj][r] *= corr;
    }
    float ls = 0.f;
    bf16x8 paA0, paA1, paB0, paB1;
#pragma unroll
    for (int r = 0; r < 4; ++r) {
      float a0 = EXP2(sA[0][r] - m_run);
      float a1 = EXP2(sA[1][r] - m_run);
      float a2 = EXP2(sA[2][r] - m_run);
      float a3 = EXP2(sA[3][r] - m_run);
      float b0 = EXP2(sB[0][r] - m_run);
      float b1 = EXP2(sB[1][r] - m_run);
      float b2 = EXP2(sB[2][r] - m_run);
      float b3 = EXP2(sB[3][r] - m_run);
      ls += ((a0 + a1) + (a2 + a3)) + ((b0 + b1) + (b2 + b3));
      paA0[r] = (bf16)a0;
      paA0[4 + r] = (bf16)a1;
      paA1[r] = (bf16)a2;
      paA1[4 + r] = (bf16)a3;
      paB0[r] = (bf16)b0;
      paB0[4 + r] = (bf16)b1;
      paB1[r] = (bf16)b2;
      paB1[4 + r] = (bf16)b3;
    }
    ls += __shfl_xor(ls, 16);
    ls += __shfl_xor(ls, 32);
    l_run += ls;
    __builtin_amdgcn_s_setprio(1);
#pragma unroll
    for (int dj = 0; dj < 4; ++dj) {
      bf16x8 vfA0 = *(bf16x8*)&Vt[bA][(dj << 4) + fr][o0];
      bf16x8 vfA1 = *(bf16x8*)&Vt[bA][(dj << 4) + fr][o1];
      oacc[dj] = __builtin_amdgcn_mfma_f32_16x16x32_bf16(vfA0, paA0, oacc[dj], 0, 0, 0);
      oacc[dj] = __builtin_amdgcn_mfma_f32_16x16x32_bf16(vfA1, paA1, oacc[dj], 0, 0, 0);
      bf16x8 vfB0 = *(bf16x8*)&Vt[bB][(dj << 4) + fr][o0];
      bf16x8 vfB1 = *(bf16x8*)&Vt[bB][(dj << 4) + fr][o1];
      oacc[dj] = __builtin_amdgcn_mfma_f32_16x16x32_bf16(vfB0, paB0, oacc[dj], 0, 0, 0);
      oacc[dj] = __builtin_amdgcn_mfma_f32_16x16x32_bf16(vfB1, paB1, oacc[dj], 0, 0, 0);
    }
    __builtin_amdgcn_s_setprio(0);
    __syncthreads();
  }
  if (TAIL) {
    // tail tile NT-1 (staged during the last pair)
    constexpr int bT = (NT - 1) & 3;
    f32x4 s[4] = {};
    __builtin_amdgcn_s_setprio(1);
#pragma unroll
    for (int nj = 0; nj < 4; ++nj) {
      bf16x8 kf0 = *(bf16x8*)&Kt[bT][(nj << 4) + fr][o0];
      bf16x8 kf1 = *(bf16x8*)&Kt[bT][(nj << 4) + fr][o1];
      s[nj] = __builtin_amdgcn_mfma_f32_16x16x32_bf16(kf0, qf0, s[nj], 0, 0, 0);
      s[nj] = __builtin_amdgcn_mfma_f32_16x16x32_bf16(kf1, qf1, s[nj], 0, 0, 0);
    }
    __builtin_amdgcn_s_setprio(0);
    float pm = fmaxf(fmaxf(s[0][0], s[0][1]), fmaxf(s[0][2], s[0][3]));
#pragma unroll
    for (int nj = 1; nj < 4; ++nj)
      pm = fmaxf(pm, fmaxf(fmaxf(s[nj][0], s[nj][1]), fmaxf(s[nj][2], s[nj][3])));
    pm = fmaxf(pm, __shfl_xor(pm, 16));
    pm = fmaxf(pm, __shfl_xor(pm, 32));
    if (__any(pm > m_run + THR_)) {
      float mn = fmaxf(m_run, pm);
      float corr = EXP2(m_run - mn);
      m_run = mn;
      l_run *= corr;
#pragma unroll
      for (int dj = 0; dj < 4; ++dj)
#pragma unroll
        for (int r = 0; r < 4; ++r) oacc[dj][r] *= corr;
    }
    float ls = 0.f;
    bf16x8 pa0, pa1;
#pragma unroll
    for (int r = 0; r < 4; ++r) {
      float p0 = EXP2(s[0][r] - m_run);
      float p1 = EXP2(s[1][r] - m_run);
      float p2 = EXP2(s[2][r] - m_run);
      float p3 = EXP2(s[3][r] - m_run);
      ls += (p0 + p1) + (p2 + p3);
      pa0[r] = (bf16)p0;
      pa0[4 + r] = (bf16)p1;
      pa1[r] = (bf16)p2;
      pa1[4 + r] = (bf16)p3;
    }
    ls += __shfl_xor(ls, 16);
    ls += __shfl_xor(ls, 32);
    l_run += ls;
    __builtin_amdgcn_s_setprio(1);
#pragma unroll
    for (int dj = 0; dj < 4; ++dj) {
      bf16x8 vf0 = *(bf16x8*)&Vt[bT][(dj << 4) + fr][o0];
      bf16x8 vf1 = *(bf16x8*)&Vt[bT][(dj << 4) + fr][o1];
      oacc[dj] = __builtin_amdgcn_mfma_f32_16x16x32_bf16(vf0, pa0, oacc[dj], 0, 0, 0);
      oacc[dj] = __builtin_amdgcn_mfma_f32_16x16x32_bf16(vf1, pa1, oacc[dj], 0, 0, 0);
    }
    __builtin_amdgcn_s_setprio(0);
  }
#undef LDK_
#undef LDV_
#undef WRT_
  long orow = (long)(split * 16 + bh) * n + q0 + (wave << 4) + fr;
#pragma unroll
  for (int dj = 0; dj < 4; ++dj) {
    bf16x4 ov = {(bf16)oacc[dj][0], (bf16)oacc[dj][1], (bf16)oacc[dj][2], (bf16)oacc[dj][3]};
    *(bf16x4*)&Op[orow * 64 + (dj << 4) + (g << 2)] = ov;
  }
  if (g == 0) {
    Mp[orow] = m_run;
    Lp[orow] = l_run;
  }
}

// ----------------------------------------------------------- split merge
template <int NS>
__global__ __launch_bounds__(256) void attn_merge_k(const bf16* __restrict__ Op,
                                                    const float* __restrict__ Mp,
                                                    const float* __restrict__ Lp,
                                                    bf16* __restrict__ aT) {
  int bh = blockIdx.y, b = bh >> 3, h = bh & 7;
  int gi = blockIdx.x * 256 + threadIdx.x;
  int nrow = gi >> 3, dd8 = (gi & 7) << 3;
  long idx[NS];
  float mm = -1e30f;
#pragma unroll
  for (int s = 0; s < NS; ++s) {
    idx[s] = (long)(s * 16 + bh) * HW_ + nrow;
    mm = fmaxf(mm, Mp[idx[s]]);
  }
  float l = 0.f, w[NS];
#pragma unroll
  for (int s = 0; s < NS; ++s) {
    w[s] = EXP2(Mp[idx[s]] - mm);
    l += Lp[idx[s]] * w[s];
  }
  float invl = 1.f / l;
  float oaccf[8] = {};
#pragma unroll
  for (int s = 0; s < NS; ++s) {
    bf16x8 o = *(const bf16x8*)&Op[idx[s] * 64 + dd8];
    float ws = w[s] * invl;
#pragma unroll
    for (int j = 0; j < 8; ++j) oaccf[j] += (float)o[j] * ws;
  }
  bf16x8 o;
#pragma unroll
  for (int j = 0; j < 8; ++j) o[j] = (bf16)oaccf[j];
  *(bf16x8*)&aT[((long)b * HW_ + nrow) * C_ + h * 64 + dd8] = o;
}

// ----------------------------------------------------------------- launch
extern "C" void kernel_launch(void* const* d_in, const int* in_sizes, int n_in,
                              void* d_out, int out_size, void* d_ws, size_t ws_size,
                              hipStream_t stream) {
  const float* x = (const float*)d_in[0];
  const float* gn_w = (const float*)d_in[1];
  const float* gn_b = (const float*)d_in[2];
  const float* qkv_w = (const float*)d_in[3];
  const float* qkv_b = (const float*)d_in[4];
  const float* proj_w = (const float*)d_in[5];
  const float* proj_b = (const float*)d_in[6];
  float* out = (float*)d_out;

  char* ws = (char*)d_ws;
  float* ps = (float*)ws;    ws += 2048;
  float* pss = (float*)ws;   ws += 2048;
  float* bqkv = (float*)ws;  ws += 6144;
  bf16* wqkv = (bf16*)ws;    ws += 1536l * 512 * 2;
  bf16* wp = (bf16*)ws;      ws += 512l * 512 * 2;
  bf16* xnT = (bf16*)ws;     ws += 2l * HW_ * 512 * 2;
  bf16* yT = (bf16*)ws;      ws += 2l * HW_ * 1024 * 2;
  bf16* v = (bf16*)ws;       ws += 2l * 512 * HW_ * 2;
  bf16* aT = (bf16*)ws;      ws += 2l * HW_ * 512 * 2;
  bf16* Op = (bf16*)ws;      // NS*16*HW*64 bf16
  size_t base_used = (size_t)(ws - (char*)d_ws);
  size_t need4 = base_used + 4ull * 16 * HW_ * 64 * 2 + 2ull * 4 * 16 * HW_ * 4;
  int NS = (ws_size >= need4) ? 4 : 2;
  ws += (size_t)NS * 16 * HW_ * 64 * 2;
  float* Mp = (float*)ws;    ws += (size_t)NS * 16 * HW_ * 4;
  float* Lp = (float*)ws;    ws += (size_t)NS * 16 * HW_ * 4;

  pre_k<<<3584, 256, 0, stream>>>(x, qkv_w, qkv_b, proj_w, ps, pss, wqkv, wp, bqkv);
  gn_apply_k<<<dim3(36, 16, 2), 256, 0, stream>>>(x, gn_w, gn_b, ps, pss, xnT);
  // fused: yT[n][0:1024) (q,k) + v[ch][n] transposed  (M=2304, N=1536, K=512)
  gemm_qkv_k<<<dim3(24, 18, 2), 512, 0, stream>>>(xnT, wqkv, bqkv, yT, v);
  if (NS == 4) {
    attn_k<4><<<dim3(18, 16, 4), 512, 0, stream>>>(yT, v, Op, Mp, Lp);
    attn_merge_k<4><<<dim3(72, 16), 256, 0, stream>>>(Op, Mp, Lp, aT);
  } else {
    attn_k<2><<<dim3(18, 16, 2), 512, 0, stream>>>(yT, v, Op, Mp, Lp);
    attn_merge_k<2><<<dim3(72, 16), 256, 0, stream>>>(Op, Mp, Lp, aT);
  }
  // out = wp @ aT^T + proj_b + x  (M=512, N=2304, K=512), fp32 out
  gemm_proj_k<<<dim3(36, 4, 2), 512, 0, stream>>>(wp, aT, proj_b, x, out);
}